// Round 8
// baseline (229.489 us; speedup 1.0000x reference)
//
#include <hip/hip_runtime.h>

#define T_STEPS 200
#define IN_DIM 1086
#define KTILES 34              // K padded to 1088
#define CHUNKS 13              // ceil(200/16) 16-row t-chunks
#define ROWPADF 1092           // LDS A row stride in floats

using f32x4v  = __attribute__((ext_vector_type(4))) float;
using bf16x8  = __attribute__((ext_vector_type(8))) short;
using u32x4   = __attribute__((ext_vector_type(4))) unsigned int;
typedef unsigned uv2 __attribute__((ext_vector_type(2)));

#if __has_builtin(__builtin_amdgcn_permlane16_swap) && __has_builtin(__builtin_amdgcn_permlane32_swap)
#define HAVE_PERMLANE_SWAP 1
#else
#define HAVE_PERMLANE_SWAP 0
#endif

#if __has_builtin(__builtin_amdgcn_exp2f)
#define EXP2F(x) __builtin_amdgcn_exp2f(x)
#else
#define EXP2F(x) exp2f(x)
#endif

__device__ __forceinline__ float rl_f(float v, int lane) {
    return __uint_as_float((unsigned)__builtin_amdgcn_readlane((int)__float_as_uint(v), lane));
}
__device__ __forceinline__ void spin_ge(int* p, int target) {
    while (__hip_atomic_load(p, __ATOMIC_ACQUIRE, __HIP_MEMORY_SCOPE_WORKGROUP) < target)
        __builtin_amdgcn_s_sleep(1);
}
__device__ __forceinline__ void arrive(int* p) {
    __hip_atomic_fetch_add(p, 1, __ATOMIC_RELEASE, __HIP_MEMORY_SCOPE_WORKGROUP);
}

// ---------------------------------------------------------------------------
// prepack_w: W_ih0[64][1086] fp32 -> hi/lo bf16, frag layout [kt][kg][64][8],
// zero-padded to K=1088. L2-resident thereafter.
// ---------------------------------------------------------------------------
__global__ __launch_bounds__(256) void prepack_w(
    const float* __restrict__ W,
    unsigned short* __restrict__ Wh, unsigned short* __restrict__ Wl)
{
    int idx = blockIdx.x * 256 + threadIdx.x;
    if (idx >= KTILES * 4 * 64 * 8) return;
    int j = idx & 7;
    int n = (idx >> 3) & 63;
    int k = (idx >> 9) * 8 + j;
    float v = (k < IN_DIM) ? W[n * IN_DIM + k] : 0.0f;
    unsigned u = __float_as_uint(v);
    unsigned hi = u & 0xffff0000u;
    float lo = v - __uint_as_float(hi);
    Wh[idx] = (unsigned short)(u >> 16);
    Wl[idx] = (unsigned short)(__float_as_uint(lo) >> 16);
}

__device__ __forceinline__ void cvt_hilo(const float (&a)[8], bf16x8& hv, bf16x8& lv) {
    union { u32x4 u; bf16x8 v; } H, L;
    #pragma unroll
    for (int p = 0; p < 4; ++p) {
        float a0 = a[2 * p], a1 = a[2 * p + 1];
        unsigned u0 = __float_as_uint(a0), u1 = __float_as_uint(a1);
        unsigned h0 = u0 & 0xffff0000u, h1 = u1 & 0xffff0000u;
        H.u[p] = (u0 >> 16) | h1;
        float l0 = a0 - __uint_as_float(h0);
        float l1 = a1 - __uint_as_float(h1);
        L.u[p] = (__float_as_uint(l0) >> 16) | (__float_as_uint(l1) & 0xffff0000u);
    }
    hv = H.v; lv = L.v;
}

// ---------------------------------------------------------------------------
// fused_all: block b = batch element. 12 waves.
//   waves 4-11: producers — per 16-row chunk: stage contiguous 69.5KB X-span
//     into LDS (512 thr x 9 dwordx4, sequential DRAM), then GEMM split
//     4nf x 2 K-halves, pair-reduce, write pre(+bias) to global pre0.
//   waves 0-3: 4-layer LSTM scan pipeline, self-timed via LDS monotone
//     counters (wave L polls progress[L-1]; wave0 polls chunkdone).
// All sync intra-block -> no dispatch-order assumptions, deterministic.
// ---------------------------------------------------------------------------
__global__ __launch_bounds__(768) void fused_all(
    const float* __restrict__ X,
    const unsigned short* __restrict__ Wh, const unsigned short* __restrict__ Wl,
    const float* __restrict__ b0v,
    const float* __restrict__ whh0,
    const float* __restrict__ wih1, const float* __restrict__ whh1, const float* __restrict__ b1,
    const float* __restrict__ wih2, const float* __restrict__ whh2, const float* __restrict__ b2,
    const float* __restrict__ wih3, const float* __restrict__ whh3, const float* __restrict__ b3,
    const float* __restrict__ w_fc1, const float* __restrict__ b_fc1,
    const float* __restrict__ w_fc2, const float* __restrict__ b_fc2,
    float* __restrict__ pre0, float* __restrict__ out)
{
    __shared__ float As[16 * ROWPADF];        // 69,888 B
    __shared__ float bufs[3][T_STEPS][16];    // 38,400 B
    __shared__ float scratch[4][64 * 4];      //  4,096 B
    __shared__ int   fl[16];                  // 0:stage_arrive 1:stage_free 2:chunkdone 3..6:updone[nf] 8..10:progress[L]

    const int b   = blockIdx.x;
    const int tid = threadIdx.x;
    const int g   = tid & 63;
    const int wv  = tid >> 6;

    if (tid < 16) fl[tid] = 0;
    if (tid < 96) { int r = tid / 6, cc = tid - r * 6; As[r * ROWPADF + 1086 + cc] = 0.0f; }
    __syncthreads();   // flags + k-pad visible; the only block-wide barrier

    if (wv >= 4) {
        // ================= producers =================
        const int wp = wv - 4, nf = wp & 3, kh = wp >> 2;
        const int fr = g & 15, kg = g >> 4;
        const int ptd = tid - 256;             // 0..511
        const int kt0 = kh * 17;
        const float bv = b0v[nf * 16 + fr];
        int r_init = (ptd * 2) / 543;          // 543 float2 per row
        int c_init = ptd * 2 - r_init * 543;

        for (int c = 0; c < CHUNKS; ++c) {
            if (c > 0) spin_ge(&fl[1], 8 * c);             // prev chunk reads done
            // ---- stage: contiguous 69,504B span, 9 dwordx4/thread
            const float4* src4 = (const float4*)(X + (size_t)(b * 200 + 16 * c) * IN_DIM);
            const int maxidx = (b == 255 && c == 12) ? 2172 : 4344;
            float4 v[9];
            #pragma unroll
            for (int p = 0; p < 9; ++p) {
                int idx = ptd + p * 512;
                if (idx < maxidx) v[p] = src4[idx];
            }
            int rr = r_init, cc = c_init;
            #pragma unroll
            for (int p = 0; p < 9; ++p) {
                int idx = ptd + p * 512;
                if (idx < maxidx) {
                    int cb = cc + 1, rb = rr;
                    if (cb == 543) { cb = 0; rb = rr + 1; }
                    *(float2*)&As[rr * ROWPADF + cc * 2] = float2{v[p].x, v[p].y};
                    *(float2*)&As[rb * ROWPADF + cb * 2] = float2{v[p].z, v[p].w};
                }
                cc += 1024;
                if (cc >= 543) { cc -= 543; ++rr; }
                if (cc >= 543) { cc -= 543; ++rr; }
            }
            if (g == 0) arrive(&fl[0]);                    // stage arrive (release)
            spin_ge(&fl[0], 8 * (c + 1));

            // ---- GEMM: my nf column-frag, my K-half, full chunk rows
            f32x4v acc;
            #pragma unroll
            for (int q = 0; q < 4; ++q) acc[q] = 0.0f;
            for (int kt = kt0; kt < kt0 + 17; ++kt) {
                const float* pa = As + fr * ROWPADF + kt * 32 + kg * 8;
                float a[8];
                *(f32x4v*)&a[0] = *(const f32x4v*)pa;
                *(f32x4v*)&a[4] = *(const f32x4v*)(pa + 4);
                bf16x8 ah, al;
                cvt_hilo(a, ah, al);
                const size_t bb = (size_t)kt * 2048 + (kg * 64 + nf * 16 + fr) * 8;
                bf16x8 bh = *(const bf16x8*)(Wh + bb);
                bf16x8 bl = *(const bf16x8*)(Wl + bb);
                acc = __builtin_amdgcn_mfma_f32_16x16x32_bf16(ah, bh, acc, 0, 0, 0);
                acc = __builtin_amdgcn_mfma_f32_16x16x32_bf16(al, bh, acc, 0, 0, 0);
                acc = __builtin_amdgcn_mfma_f32_16x16x32_bf16(ah, bl, acc, 0, 0, 0);
            }
            if (g == 0) arrive(&fl[1]);                    // As reads done (release)

            if (kh == 1) {
                *(f32x4v*)&scratch[nf][g * 4] = acc;
                if (g == 0) arrive(&fl[3 + nf]);
            } else {
                spin_ge(&fl[3 + nf], c + 1);
                f32x4v o = *(const f32x4v*)&scratch[nf][g * 4];
                #pragma unroll
                for (int q = 0; q < 4; ++q) {
                    int t = 16 * c + kg * 4 + q;
                    if (t < T_STEPS)
                        pre0[((size_t)b * T_STEPS + t) * 64 + nf * 16 + fr] = acc[q] + o[q] + bv;
                }
                __threadfence_block();
                if (g == 0) arrive(&fl[2]);                // chunkdone (4/chunk)
            }
        }
        return;
    }

    // ================= scan pipeline (waves 0-3) =================
    bool sel16 = false, sel32 = false;
#if HAVE_PERMLANE_SWAP
    {
        uv2 q16 = __builtin_amdgcn_permlane16_swap((unsigned)g, (unsigned)g, false, false);
        sel16 = (__builtin_amdgcn_readfirstlane((int)q16[1]) == 16);
        uv2 q32 = __builtin_amdgcn_permlane32_swap((unsigned)g, (unsigned)g, false, false);
        sel32 = (__builtin_amdgcn_readfirstlane((int)q32[1]) == 32);
    }
#endif
    const float* wih = nullptr; const float* whh; const float* bias = nullptr;
    if      (wv == 0) { whh = whh0; }
    else if (wv == 1) { wih = wih1; whh = whh1; bias = b1; }
    else if (wv == 2) { wih = wih2; whh = whh2; bias = b2; }
    else              { wih = wih3; whh = whh3; bias = b3; }

    float whh_r[16];
    #pragma unroll
    for (int q = 0; q < 4; ++q)
        *(float4*)&whh_r[q * 4] = *(const float4*)&whh[g * 16 + q * 4];
    float wih_r[16]; float bg = 0.0f;
    if (wv) {
        #pragma unroll
        for (int q = 0; q < 4; ++q)
            *(float4*)&wih_r[q * 4] = *(const float4*)&wih[g * 16 + q * 4];
        bg = bias[g];
    }

    float hs[16];
    #pragma unroll
    for (int k = 0; k < 16; ++k) hs[k] = 0.0f;
    float cst = 0.0f;

    const int q4 = g >> 4;
    const float escale = (q4 == 2) ? -2.8853900817779268f : -1.4426950408889634f;
    const float am = (q4 == 2) ? 2.0f : 1.0f;
    const float aa = (q4 == 2) ? -1.0f : 0.0f;

    const float* pb = pre0 + (size_t)b * T_STEPS * 64 + g;
    float pc = 0.0f, p1 = 0.0f, p2 = 0.0f;
    if (wv == 0) {
        spin_ge(&fl[2], 4);                    // chunk 0 ready
        pc = pb[0]; p1 = pb[64]; p2 = pb[128];
    }

    for (int t = 0; t < T_STEPS; ++t) {
        float acc;
        if (wv == 0) {
            if ((t & 15) == 12 && t < 192) spin_ge(&fl[2], 4 * ((t >> 4) + 2));
            acc = pc;
            float r0 = fmaf(whh_r[0], hs[0], acc);
            float r1 = whh_r[1] * hs[1];
            float r2 = whh_r[2] * hs[2];
            float r3 = whh_r[3] * hs[3];
            #pragma unroll
            for (int k = 4; k < 16; k += 4) {
                r0 = fmaf(whh_r[k + 0], hs[k + 0], r0);
                r1 = fmaf(whh_r[k + 1], hs[k + 1], r1);
                r2 = fmaf(whh_r[k + 2], hs[k + 2], r2);
                r3 = fmaf(whh_r[k + 3], hs[k + 3], r3);
            }
            acc = (r0 + r1) + (r2 + r3);
        } else {
            spin_ge(&fl[8 + wv - 1], t + 1);   // predecessor layer published t
            float xr[16];
            #pragma unroll
            for (int q = 0; q < 4; ++q)
                *(float4*)&xr[q * 4] = *(const float4*)&bufs[wv - 1][t][q * 4];
            float r0 = fmaf(whh_r[0], hs[0], bg);
            float r1 = whh_r[1] * hs[1];
            float r2 = whh_r[2] * hs[2];
            float r3 = whh_r[3] * hs[3];
            #pragma unroll
            for (int k = 4; k < 16; k += 4) {
                r0 = fmaf(whh_r[k + 0], hs[k + 0], r0);
                r1 = fmaf(whh_r[k + 1], hs[k + 1], r1);
                r2 = fmaf(whh_r[k + 2], hs[k + 2], r2);
                r3 = fmaf(whh_r[k + 3], hs[k + 3], r3);
            }
            float p0 = wih_r[0] * xr[0];
            float q1 = wih_r[1] * xr[1];
            float q2 = wih_r[2] * xr[2];
            float q3 = wih_r[3] * xr[3];
            #pragma unroll
            for (int k = 4; k < 16; k += 4) {
                p0 = fmaf(wih_r[k + 0], xr[k + 0], p0);
                q1 = fmaf(wih_r[k + 1], xr[k + 1], q1);
                q2 = fmaf(wih_r[k + 2], xr[k + 2], q2);
                q3 = fmaf(wih_r[k + 3], xr[k + 3], q3);
            }
            acc = ((r0 + r1) + (r2 + r3)) + ((p0 + q1) + (q2 + q3));
        }

        float e = EXP2F(escale * acc);
        float s = __builtin_amdgcn_rcpf(1.0f + e);
        float a = fmaf(am, s, aa);
#if HAVE_PERMLANE_SWAP
        unsigned au = __float_as_uint(a);
        uv2 r16 = __builtin_amdgcn_permlane16_swap(au, au, false, false);
        uv2 r32 = __builtin_amdgcn_permlane32_swap(au, au, false, false);
        unsigned fvu = sel16 ? r16[1] : r16[0];
        unsigned gvu = sel32 ? r32[1] : r32[0];
        uv2 r48 = __builtin_amdgcn_permlane16_swap(gvu, gvu, false, false);
        unsigned ovu = sel16 ? r48[1] : r48[0];
        float fv = __uint_as_float(fvu);
        float gv = __uint_as_float(gvu);
        float ov = __uint_as_float(ovu);
#else
        float fv = __shfl_xor(a, 16, 64);
        float gv = __shfl_xor(a, 32, 64);
        float ov = __shfl_xor(a, 48, 64);
#endif
        cst = fmaf(fv, cst, a * gv);
        float e2 = EXP2F(-2.8853900817779268f * cst);
        float s2 = __builtin_amdgcn_rcpf(1.0f + e2);
        float hn = fmaf(ov + ov, s2, -ov);
        if (wv < 3 && g < 16) bufs[wv][t][g] = hn;
        if (wv < 3 && g == 0)
            __hip_atomic_store(&fl[8 + wv], t + 1, __ATOMIC_RELEASE, __HIP_MEMORY_SCOPE_WORKGROUP);
        #pragma unroll
        for (int k = 0; k < 16; ++k) hs[k] = rl_f(hn, k);
        if (wv == 0) {
            pc = p1; p1 = p2;
            int tn = (t + 3 < T_STEPS) ? t + 3 : T_STEPS - 1;
            p2 = pb[(size_t)tn * 64];
        }
    }

    // ---- head: fc1+relu -> fc2 -> softmax(15), wave3 only
    if (wv == 3 && g < 16) {
        float a1 = b_fc1[g];
        #pragma unroll
        for (int k = 0; k < 16; ++k) a1 = fmaf(w_fc1[g * 16 + k], hs[k], a1);
        a1 = fmaxf(a1, 0.0f);
        float h1[16];
        #pragma unroll
        for (int k = 0; k < 16; ++k) h1[k] = rl_f(a1, k);
        float lg = -3.0e38f;
        if (g < 15) {
            lg = b_fc2[g];
            #pragma unroll
            for (int k = 0; k < 16; ++k) lg = fmaf(w_fc2[g * 16 + k], h1[k], lg);
        }
        float mx = lg;
        #pragma unroll
        for (int d = 8; d >= 1; d >>= 1) mx = fmaxf(mx, __shfl_xor(mx, d, 16));
        float ev = (g < 15) ? EXP2F(1.4426950408889634f * (lg - mx)) : 0.0f;
        float sm = ev;
        #pragma unroll
        for (int d = 8; d >= 1; d >>= 1) sm += __shfl_xor(sm, d, 16);
        if (g < 15) out[b * 15 + g] = ev * __builtin_amdgcn_rcpf(sm);
    }
}

extern "C" void kernel_launch(void* const* d_in, const int* in_sizes, int n_in,
                              void* d_out, int out_size, void* d_ws, size_t ws_size,
                              hipStream_t stream) {
    const float* x    = (const float*)d_in[0];
    const float* wih0 = (const float*)d_in[1];
    const float* whh0 = (const float*)d_in[2];
    const float* b0   = (const float*)d_in[3];
    const float* wih1 = (const float*)d_in[4];
    const float* whh1 = (const float*)d_in[5];
    const float* b1   = (const float*)d_in[6];
    const float* wih2 = (const float*)d_in[7];
    const float* whh2 = (const float*)d_in[8];
    const float* b2   = (const float*)d_in[9];
    const float* wih3 = (const float*)d_in[10];
    const float* whh3 = (const float*)d_in[11];
    const float* b3   = (const float*)d_in[12];
    const float* wfc1 = (const float*)d_in[13];
    const float* bfc1 = (const float*)d_in[14];
    const float* wfc2 = (const float*)d_in[15];
    const float* bfc2 = (const float*)d_in[16];

    float* pre0 = (float*)d_ws;                                       // 13,107,200 B
    unsigned short* Wh = (unsigned short*)((char*)d_ws + 13107200);   // 139,264 B
    unsigned short* Wl = (unsigned short*)((char*)d_ws + 13107200 + 139264);

    prepack_w<<<dim3((KTILES * 4 * 64 * 8 + 255) / 256), dim3(256), 0, stream>>>(wih0, Wh, Wl);
    fused_all<<<dim3(256), dim3(768), 0, stream>>>(x, Wh, Wl, b0,
        whh0, wih1, whh1, b1, wih2, whh2, b2, wih3, whh3, b3,
        wfc1, bfc1, wfc2, bfc2, pre0, (float*)d_out);
}

// Round 9
// 167.095 us; speedup vs baseline: 1.3734x; 1.3734x over previous
//
#include <hip/hip_runtime.h>

#define T_STEPS 200
#define IN_DIM 1086
#define KTILES 34              // K padded to 1088
#define M_TOTAL 51200          // 256*200

using f32x4v  = __attribute__((ext_vector_type(4))) float;
using bf16x8  = __attribute__((ext_vector_type(8))) short;
using u32x4   = __attribute__((ext_vector_type(4))) unsigned int;
typedef unsigned uv2 __attribute__((ext_vector_type(2)));

#if __has_builtin(__builtin_amdgcn_permlane16_swap) && __has_builtin(__builtin_amdgcn_permlane32_swap)
#define HAVE_PERMLANE_SWAP 1
#else
#define HAVE_PERMLANE_SWAP 0
#endif

#if __has_builtin(__builtin_amdgcn_exp2f)
#define EXP2F(x) __builtin_amdgcn_exp2f(x)
#else
#define EXP2F(x) exp2f(x)
#endif

// global_load_lds: per-lane GLOBAL source, wave-uniform LDS base + lane*size.
#define GLDS(gp, lp, sz) __builtin_amdgcn_global_load_lds(                         \
    (const __attribute__((address_space(1))) unsigned int*)(gp),                   \
    (__attribute__((address_space(3))) unsigned int*)(lp), sz, 0, 0)

__device__ __forceinline__ float rl_f(float v, int lane) {
    return __uint_as_float((unsigned)__builtin_amdgcn_readlane((int)__float_as_uint(v), lane));
}

// ---------------------------------------------------------------------------
// prepack_w: W_ih0[64][1086] fp32 -> hi/lo bf16, frag layout [kt][kg][64][8],
// zero-padded to K=1088 (so A-tail garbage multiplies by 0). L2-resident.
// ---------------------------------------------------------------------------
__global__ __launch_bounds__(256) void prepack_w(
    const float* __restrict__ W,
    unsigned short* __restrict__ Wh, unsigned short* __restrict__ Wl)
{
    int idx = blockIdx.x * 256 + threadIdx.x;
    if (idx >= KTILES * 4 * 64 * 8) return;
    int j = idx & 7;
    int n = (idx >> 3) & 63;
    int k = (idx >> 9) * 8 + j;
    float v = (k < IN_DIM) ? W[n * IN_DIM + k] : 0.0f;
    unsigned u = __float_as_uint(v);
    unsigned hi = u & 0xffff0000u;
    float lo = v - __uint_as_float(hi);
    Wh[idx] = (unsigned short)(u >> 16);
    Wl[idx] = (unsigned short)(__float_as_uint(lo) >> 16);
}

__device__ __forceinline__ void cvt_hilo(const float (&a)[8], bf16x8& hv, bf16x8& lv) {
    union { u32x4 u; bf16x8 v; } H, L;
    #pragma unroll
    for (int p = 0; p < 4; ++p) {
        float a0 = a[2 * p], a1 = a[2 * p + 1];
        unsigned u0 = __float_as_uint(a0), u1 = __float_as_uint(a1);
        unsigned h0 = u0 & 0xffff0000u, h1 = u1 & 0xffff0000u;
        H.u[p] = (u0 >> 16) | h1;
        float l0 = a0 - __uint_as_float(h0);
        float l1 = a1 - __uint_as_float(h1);
        L.u[p] = (__float_as_uint(l0) >> 16) | (__float_as_uint(l1) & 0xffff0000u);
    }
    hv = H.v; lv = L.v;
}

// ---------------------------------------------------------------------------
// pre0_gemm_v5: m97-schedule. BM=64, BK=32, 4 waves, double-buffered LDS,
// global_load_lds staging (A size-4: X rows only 8B-aligned; B size-16).
// Loop: barrier (drains PREV iter's glds) -> fire glds for kt+1 -> compute kt.
// Loads for kt+1 stay in flight across the whole compute of kt.
// A LDS layout: dword D = r*32 + s*4 + d holds k-dword (s^(r&7))*4+d
// (source-side XOR swizzle since glds dest is linear) -> frag ds_read_b128
// is 2-lanes/bank = free.
// ---------------------------------------------------------------------------
__global__ __launch_bounds__(256) void pre0_gemm_v5(
    const float* __restrict__ X,
    const unsigned short* __restrict__ Wh, const unsigned short* __restrict__ Wl,
    const float* __restrict__ bias, float* __restrict__ out)
{
    __shared__ float          As[2][2048];      // [buf][r*32+k'] 16KB
    __shared__ unsigned short Bs[2][2][2048];   // [buf][h/l][kg*64*8..] 16KB

    const int tid  = threadIdx.x;
    const int lane = tid & 63;
    const int wv   = tid >> 6;
    const int fr   = lane & 15;
    const int kg   = lane >> 4;
    const long m0  = (long)blockIdx.x * 64;

    // ---- staging geometry (per lane): inst i covers row rbase+2i
    const int rbase = wv * 16 + (lane >> 5);       // rows: 2 halves of wave
    const int sidx  = (lane >> 2) & 7;             // LDS 16B-slot within row
    const int dsub  = lane & 3;                    // dword within slot
    int koff[8];                                   // k-byte offset per inst (XOR-swizzled)
    #pragma unroll
    for (int i = 0; i < 8; ++i)
        koff[i] = ((sidx ^ ((rbase + 2 * i) & 7)) * 4 + dsub) * 4;
    const char* Xrow = (const char*)X + (m0 + rbase) * 4344;

    f32x4v acc[4];
    #pragma unroll
    for (int nf = 0; nf < 4; ++nf)
        #pragma unroll
        for (int r = 0; r < 4; ++r) acc[nf][r] = 0.0f;

    // ---- prologue: stage kt=0 into buf 0
    {
        #pragma unroll
        for (int i = 0; i < 8; ++i) {
            int off = koff[i];                                    // kt=0: no clamp needed
            GLDS(Xrow + (long)i * 8688 + off, &As[0][wv * 512 + i * 64], 4);
        }
        GLDS(Wh + tid * 8, (char*)Bs[0][0] + wv * 1024, 16);
        GLDS(Wl + tid * 8, (char*)Bs[0][1] + wv * 1024, 16);
    }

    for (int kt = 0; kt < KTILES; ++kt) {
        const int cur = kt & 1;
        __syncthreads();               // drains prev-iter glds -> buf[cur] ready

        if (kt + 1 < KTILES) {         // fire kt+1 into buf[cur^1]; flies over compute
            const int nb = cur ^ 1, kb = (kt + 1) * 128;
            #pragma unroll
            for (int i = 0; i < 8; ++i) {
                int off = kb + koff[i];
                off = off > 4340 ? 4340 : off;   // tail: k=1086/1087 -> safe addr, x*0=0
                GLDS(Xrow + (long)i * 8688 + off, &As[nb][wv * 512 + i * 64], 4);
            }
            GLDS(Wh + (size_t)(kt + 1) * 2048 + tid * 8, (char*)Bs[nb][0] + wv * 1024, 16);
            GLDS(Wl + (size_t)(kt + 1) * 2048 + tid * 8, (char*)Bs[nb][1] + wv * 1024, 16);
        }

        // ---- compute buf[cur]
        const int r  = wv * 16 + fr;
        const int r7 = r & 7;
        const float* pa1 = &As[cur][r * 32 + (((2 * kg) ^ r7) << 2)];
        const float* pa2 = &As[cur][r * 32 + ((((2 * kg) | 1) ^ r7) << 2)];
        float a[8];
        *(f32x4v*)&a[0] = *(const f32x4v*)pa1;
        *(f32x4v*)&a[4] = *(const f32x4v*)pa2;
        bf16x8 ah, al;
        cvt_hilo(a, ah, al);
        #pragma unroll
        for (int nf = 0; nf < 4; ++nf) {
            const int bofs = (kg * 64 + nf * 16 + fr) * 8;
            bf16x8 bh = *(const bf16x8*)&Bs[cur][0][bofs];
            bf16x8 bl = *(const bf16x8*)&Bs[cur][1][bofs];
            acc[nf] = __builtin_amdgcn_mfma_f32_16x16x32_bf16(ah, bh, acc[nf], 0, 0, 0);
            acc[nf] = __builtin_amdgcn_mfma_f32_16x16x32_bf16(al, bh, acc[nf], 0, 0, 0);
            acc[nf] = __builtin_amdgcn_mfma_f32_16x16x32_bf16(ah, bl, acc[nf], 0, 0, 0);
        }
    }

    // ---- epilogue: +bias, fp32 store. C/D map: col=lane&15, row=(lane>>4)*4+r
    float bvv[4];
    #pragma unroll
    for (int nf = 0; nf < 4; ++nf) bvv[nf] = bias[nf * 16 + fr];
    #pragma unroll
    for (int nf = 0; nf < 4; ++nf)
        #pragma unroll
        for (int rr = 0; rr < 4; ++rr) {
            long row = m0 + wv * 16 + kg * 4 + rr;
            out[row * 64 + nf * 16 + fr] = acc[nf][rr] + bvv[nf];
        }
}

// ---------------------------------------------------------------------------
// mega_scan: 4-wave layer pipeline (R6 verbatim — ~45us).
// ---------------------------------------------------------------------------
__global__ __launch_bounds__(256) void mega_scan(
    const float* __restrict__ pre0, const float* __restrict__ whh0,
    const float* __restrict__ wih1, const float* __restrict__ whh1, const float* __restrict__ b1,
    const float* __restrict__ wih2, const float* __restrict__ whh2, const float* __restrict__ b2,
    const float* __restrict__ wih3, const float* __restrict__ whh3, const float* __restrict__ b3,
    const float* __restrict__ w_fc1, const float* __restrict__ b_fc1,
    const float* __restrict__ w_fc2, const float* __restrict__ b_fc2,
    float* __restrict__ out)
{
    __shared__ float buf[3][T_STEPS][16];

    const int b    = blockIdx.x;
    const int tid  = threadIdx.x;
    const int g    = tid & 63;
    const int wv   = tid >> 6;

    bool sel16 = false, sel32 = false;
#if HAVE_PERMLANE_SWAP
    {
        uv2 q16 = __builtin_amdgcn_permlane16_swap((unsigned)g, (unsigned)g, false, false);
        sel16 = (__builtin_amdgcn_readfirstlane((int)q16[1]) == 16);
        uv2 q32 = __builtin_amdgcn_permlane32_swap((unsigned)g, (unsigned)g, false, false);
        sel32 = (__builtin_amdgcn_readfirstlane((int)q32[1]) == 32);
    }
#endif

    const float* wih = nullptr; const float* whh; const float* bias = nullptr;
    if      (wv == 0) { whh = whh0; }
    else if (wv == 1) { wih = wih1; whh = whh1; bias = b1; }
    else if (wv == 2) { wih = wih2; whh = whh2; bias = b2; }
    else              { wih = wih3; whh = whh3; bias = b3; }

    float whh_r[16];
    #pragma unroll
    for (int q = 0; q < 4; ++q)
        *(float4*)&whh_r[q * 4] = *(const float4*)&whh[g * 16 + q * 4];
    float wih_r[16]; float bg = 0.0f;
    if (wv) {
        #pragma unroll
        for (int q = 0; q < 4; ++q)
            *(float4*)&wih_r[q * 4] = *(const float4*)&wih[g * 16 + q * 4];
        bg = bias[g];
    }

    const float* pb = pre0 + (size_t)b * T_STEPS * 64 + g;
    float pc = 0.0f, p1 = 0.0f, p2 = 0.0f;
    if (wv == 0) { pc = pb[0]; p1 = pb[64]; p2 = pb[128]; }

    float hs[16];
    #pragma unroll
    for (int k = 0; k < 16; ++k) hs[k] = 0.0f;
    float c = 0.0f;

    const int q4 = g >> 4;
    const float escale = (q4 == 2) ? -2.8853900817779268f : -1.4426950408889634f;
    const float am = (q4 == 2) ? 2.0f : 1.0f;
    const float aa = (q4 == 2) ? -1.0f : 0.0f;

    for (int tau = 0; tau < T_STEPS + 3; ++tau) {
        __syncthreads();
        const int t = tau - wv;
        if (t >= 0 && t < T_STEPS) {
            float xr[16];
            if (wv) {
                #pragma unroll
                for (int q = 0; q < 4; ++q)
                    *(float4*)&xr[q * 4] = *(const float4*)&buf[wv - 1][t][q * 4];
            }
            float r0 = fmaf(whh_r[0], hs[0], wv ? bg : pc);
            float r1 = whh_r[1] * hs[1];
            float r2 = whh_r[2] * hs[2];
            float r3 = whh_r[3] * hs[3];
            #pragma unroll
            for (int k = 4; k < 16; k += 4) {
                r0 = fmaf(whh_r[k + 0], hs[k + 0], r0);
                r1 = fmaf(whh_r[k + 1], hs[k + 1], r1);
                r2 = fmaf(whh_r[k + 2], hs[k + 2], r2);
                r3 = fmaf(whh_r[k + 3], hs[k + 3], r3);
            }
            float acc = (r0 + r1) + (r2 + r3);
            if (wv) {
                float p0 = wih_r[0] * xr[0];
                float q1 = wih_r[1] * xr[1];
                float q2 = wih_r[2] * xr[2];
                float q3 = wih_r[3] * xr[3];
                #pragma unroll
                for (int k = 4; k < 16; k += 4) {
                    p0 = fmaf(wih_r[k + 0], xr[k + 0], p0);
                    q1 = fmaf(wih_r[k + 1], xr[k + 1], q1);
                    q2 = fmaf(wih_r[k + 2], xr[k + 2], q2);
                    q3 = fmaf(wih_r[k + 3], xr[k + 3], q3);
                }
                acc += (p0 + q1) + (q2 + q3);
            }
            float e = EXP2F(escale * acc);
            float s = __builtin_amdgcn_rcpf(1.0f + e);
            float a = fmaf(am, s, aa);
#if HAVE_PERMLANE_SWAP
            unsigned au = __float_as_uint(a);
            uv2 r16 = __builtin_amdgcn_permlane16_swap(au, au, false, false);
            uv2 r32 = __builtin_amdgcn_permlane32_swap(au, au, false, false);
            unsigned fvu = sel16 ? r16[1] : r16[0];
            unsigned gvu = sel32 ? r32[1] : r32[0];
            uv2 r48 = __builtin_amdgcn_permlane16_swap(gvu, gvu, false, false);
            unsigned ovu = sel16 ? r48[1] : r48[0];
            float fv = __uint_as_float(fvu);
            float gv = __uint_as_float(gvu);
            float ov = __uint_as_float(ovu);
#else
            float fv = __shfl_xor(a, 16, 64);
            float gv = __shfl_xor(a, 32, 64);
            float ov = __shfl_xor(a, 48, 64);
#endif
            c = fmaf(fv, c, a * gv);
            float e2 = EXP2F(-2.8853900817779268f * c);
            float s2 = __builtin_amdgcn_rcpf(1.0f + e2);
            float hn = fmaf(ov + ov, s2, -ov);
            if (wv < 3 && g < 16) buf[wv][t][g] = hn;
            #pragma unroll
            for (int k = 0; k < 16; ++k) hs[k] = rl_f(hn, k);
            if (wv == 0) {
                pc = p1; p1 = p2;
                int tn = t + 3; tn = tn < T_STEPS ? tn : T_STEPS - 1;
                p2 = pb[(size_t)tn * 64];
            }
        }
    }

    if (wv == 3 && g < 16) {
        float a1 = b_fc1[g];
        #pragma unroll
        for (int k = 0; k < 16; ++k) a1 = fmaf(w_fc1[g * 16 + k], hs[k], a1);
        a1 = fmaxf(a1, 0.0f);
        float h1[16];
        #pragma unroll
        for (int k = 0; k < 16; ++k) h1[k] = rl_f(a1, k);
        float lg = -3.0e38f;
        if (g < 15) {
            lg = b_fc2[g];
            #pragma unroll
            for (int k = 0; k < 16; ++k) lg = fmaf(w_fc2[g * 16 + k], h1[k], lg);
        }
        float mx = lg;
        #pragma unroll
        for (int d = 8; d >= 1; d >>= 1) mx = fmaxf(mx, __shfl_xor(mx, d, 16));
        float ev = (g < 15) ? EXP2F(1.4426950408889634f * (lg - mx)) : 0.0f;
        float sm = ev;
        #pragma unroll
        for (int d = 8; d >= 1; d >>= 1) sm += __shfl_xor(sm, d, 16);
        if (g < 15) out[b * 15 + g] = ev * __builtin_amdgcn_rcpf(sm);
    }
}

extern "C" void kernel_launch(void* const* d_in, const int* in_sizes, int n_in,
                              void* d_out, int out_size, void* d_ws, size_t ws_size,
                              hipStream_t stream) {
    const float* x    = (const float*)d_in[0];
    const float* wih0 = (const float*)d_in[1];
    const float* whh0 = (const float*)d_in[2];
    const float* b0   = (const float*)d_in[3];
    const float* wih1 = (const float*)d_in[4];
    const float* whh1 = (const float*)d_in[5];
    const float* b1   = (const float*)d_in[6];
    const float* wih2 = (const float*)d_in[7];
    const float* whh2 = (const float*)d_in[8];
    const float* b2   = (const float*)d_in[9];
    const float* wih3 = (const float*)d_in[10];
    const float* whh3 = (const float*)d_in[11];
    const float* b3   = (const float*)d_in[12];
    const float* wfc1 = (const float*)d_in[13];
    const float* bfc1 = (const float*)d_in[14];
    const float* wfc2 = (const float*)d_in[15];
    const float* bfc2 = (const float*)d_in[16];

    float* pre0 = (float*)d_ws;                                       // 13,107,200 B
    unsigned short* Wh = (unsigned short*)((char*)d_ws + 13107200);   // 139,264 B
    unsigned short* Wl = (unsigned short*)((char*)d_ws + 13107200 + 139264);

    prepack_w<<<dim3((KTILES * 4 * 64 * 8 + 255) / 256), dim3(256), 0, stream>>>(wih0, Wh, Wl);
    pre0_gemm_v5<<<dim3(M_TOTAL / 64), dim3(256), 0, stream>>>(x, Wh, Wl, b0, pre0);
    mega_scan<<<dim3(256), dim3(256), 0, stream>>>(pre0, whh0,
        wih1, whh1, b1, wih2, whh2, b2, wih3, whh3, b3,
        wfc1, bfc1, wfc2, bfc2, (float*)d_out);
}